// Round 16
// baseline (542.762 us; speedup 1.0000x reference)
//
#include <hip/hip_runtime.h>
#include <hip/hip_fp16.h>
#include <math.h>

#define D_FEAT 128
#define EPS 1e-12f
#define TGRP 40        // targets per bucket -> LDS acc = 40*128*4 = 20 KB
#define NBUCK_PAD 256  // padded bucket count (n <= 10240)
#define NBLK 250       // edge chunks; EPB = E/NBLK = 2560
#define EPB_MAX 2560   // LDS staging capacity in partition kernel

// ===========================================================================
// out = normalize(relu(sum_e ew_e * x_src)) — 1/deg cancels in the normalize.
// R16 redesign around the measured cost model:
//   * scattered 4-8 B stores cost ~53 B write-through EACH (R8: 34 MB WRITE
//     for 2.6 MB logical; R11 XCD-replication didn't help -> per-store
//     granularity, not coherence). => ALL bulk writes are LDS-staged and
//     coalesced.
//   * per-row gather waves serialize ~64 shuffle rounds. => replace with
//     per-bucket streaming accumulate into an LDS fp32 accumulator.
// Pipeline (4 dispatches, no memsets, zero global atomics):
//   P1 count+convert: per-chunk LDS hist over 250 buckets -> cntb u16.
//   PB prefix: baseb[chunk][bucket] u16, bucketptr[bucket] u32 (1 block).
//   P2 partition: chunk sorted by bucket in LDS; payload (src<<16|fp16w,
//      tloc) written COALESCED in per-(chunk,bucket) runs.
//   P3 accumulate+norm: block b streams segment [bucketptr[b],bucketptr[b+1])
//      (coalesced reads), ds_add_f32 into acc[40][128], then relu + L2 norm
//      + coalesced store.
// ===========================================================================

__device__ inline float2 h2_to_f2(unsigned int u) {
    __half2 h = *reinterpret_cast<__half2*>(&u);
    return __half22float2(h);
}

// ---------------------------------------------------------------------------
// P1: per-chunk bucket histogram + fused x fp32->fp16 convert.
// ---------------------------------------------------------------------------
__global__ __launch_bounds__(1024)
void count_convert_kernel(const int* __restrict__ edge_i,
                          const float* __restrict__ x,
                          unsigned int* __restrict__ xh,
                          unsigned short* __restrict__ cntb,  // [NBLK][NBUCK_PAD]
                          int E, int total4) {
    __shared__ unsigned int hc[NBUCK_PAD];
    const int b   = blockIdx.x;
    const int tid = threadIdx.x;
    const int EPB = E / NBLK;

    if (tid < NBUCK_PAD) hc[tid] = 0;
    __syncthreads();

    // fused convert (grid-stride)
    for (int i = b * 1024 + tid; i < total4; i += NBLK * 1024) {
        float4 v = ((const float4*)x)[i];
        __half2 h01 = __floats2half2_rn(v.x, v.y);
        __half2 h23 = __floats2half2_rn(v.z, v.w);
        uint2 o;
        o.x = *reinterpret_cast<unsigned int*>(&h01);
        o.y = *reinterpret_cast<unsigned int*>(&h23);
        ((uint2*)xh)[i] = o;
    }

    const int e0 = b * EPB;
    for (int k = tid; k < EPB; k += 1024)
        atomicAdd(&hc[edge_i[e0 + k] / TGRP], 1u);
    __syncthreads();

    if (tid < NBUCK_PAD)
        cntb[(size_t)b * NBUCK_PAD + tid] =
            (unsigned short)(hc[tid] > 65535u ? 65535u : hc[tid]);
}

// ---------------------------------------------------------------------------
// PB: per-bucket prefix over chunks (baseb) + bucket offsets (bucketptr).
// Single block of 256 threads; tiny (125 KB of u16 traffic).
// ---------------------------------------------------------------------------
__global__ __launch_bounds__(256)
void prefix_kernel(const unsigned short* __restrict__ cntb,
                   unsigned short* __restrict__ baseb,   // [NBLK][NBUCK_PAD]
                   unsigned int* __restrict__ bucketptr, // [nbuck+1]
                   int nbuck) {
    __shared__ unsigned int s[256];
    const int tid = threadIdx.x;
    unsigned int tot = 0;
    if (tid < nbuck) {
        for (int c = 0; c < NBLK; ++c) {
            unsigned int v = cntb[(size_t)c * NBUCK_PAD + tid];
            baseb[(size_t)c * NBUCK_PAD + tid] = (unsigned short)tot;
            tot += v;
        }
    }
    s[tid] = (tid < nbuck) ? tot : 0;
    __syncthreads();
    for (int off = 1; off < 256; off <<= 1) {
        unsigned int v = (tid >= off) ? s[tid - off] : 0;
        __syncthreads();
        s[tid] += v;
        __syncthreads();
    }
    if (tid < nbuck) bucketptr[tid] = s[tid] - tot;  // exclusive
    if (tid == 255) bucketptr[nbuck] = s[255];       // grand total
}

// ---------------------------------------------------------------------------
// P2: partition. Chunk's edges sorted by bucket in LDS, then written out
// coalesced: run for (chunk,bucket) is contiguous at
// bucketptr[bkt] + baseb[chunk][bkt]. Payload = uint2{src<<16|fp16(w), tloc}.
// ---------------------------------------------------------------------------
__global__ __launch_bounds__(1024)
void partition_kernel(const int* __restrict__ edge_i,
                      const int* __restrict__ edge_j,
                      const float* __restrict__ ew,
                      const unsigned short* __restrict__ baseb,
                      const unsigned int* __restrict__ bucketptr,
                      uint2* __restrict__ payload, int E) {
    __shared__ unsigned int hc[NBUCK_PAD];
    __shared__ unsigned int hbase[NBUCK_PAD];
    __shared__ unsigned int stmp[NBUCK_PAD];
    __shared__ uint2        sp[EPB_MAX];     // 20 KB
    __shared__ unsigned int sdst[EPB_MAX];   // 10 KB
    const int b   = blockIdx.x;
    const int tid = threadIdx.x;
    const int EPB = E / NBLK;
    const int e0  = b * EPB;

    if (tid < NBUCK_PAD) hc[tid] = 0;
    __syncthreads();

    // pass 1: local rank per edge within (chunk,bucket); carry in registers
    int tcar[3]; unsigned int rcar[3]; int kcar[3]; int ncar = 0;
    for (int k = tid; k < EPB; k += 1024) {
        int t = edge_i[e0 + k];
        unsigned int r = atomicAdd(&hc[t / TGRP], 1u);
        tcar[ncar] = t; rcar[ncar] = r; kcar[ncar] = k; ++ncar;
    }
    __syncthreads();

    // exclusive scan of hc -> hbase (all 1024 threads hit the barriers)
    unsigned int own = (tid < NBUCK_PAD) ? hc[tid] : 0;
    if (tid < NBUCK_PAD) stmp[tid] = own;
    __syncthreads();
    for (int off = 1; off < NBUCK_PAD; off <<= 1) {
        unsigned int v = (tid >= off && tid < NBUCK_PAD) ? stmp[tid - off] : 0;
        __syncthreads();
        if (tid < NBUCK_PAD) stmp[tid] += v;
        __syncthreads();
    }
    if (tid < NBUCK_PAD) hbase[tid] = stmp[tid] - own;
    __syncthreads();

    // pass 2: stage sorted payload + destination
    for (int c = 0; c < ncar; ++c) {
        int t = tcar[c];
        int k = kcar[c];
        unsigned int r = rcar[c];
        int bkt  = t / TGRP;
        int tloc = t - bkt * TGRP;
        int e = e0 + k;
        unsigned short hw = __half_as_ushort(__float2half(ew[e]));
        unsigned int lpos = hbase[bkt] + r;
        sp[lpos]   = make_uint2(((unsigned int)edge_j[e] << 16) | (unsigned int)hw,
                                (unsigned int)tloc);
        sdst[lpos] = bucketptr[bkt] + (unsigned int)baseb[(size_t)b * NBUCK_PAD + bkt] + r;
    }
    __syncthreads();

    // coalesced write-out: consecutive lpos in a run -> consecutive dst
    for (int k = tid; k < EPB; k += 1024)
        payload[sdst[k]] = sp[k];
}

// ---------------------------------------------------------------------------
// P3: per-bucket accumulate + relu + L2 normalize. Block b streams its
// contiguous payload segment; wave processes one edge per shuffle round
// (64 lanes x 2 feats = 128); 4-deep load staging; LDS fp32 atomicAdd.
// ---------------------------------------------------------------------------
__global__ __launch_bounds__(1024)
void accum_norm_kernel(const unsigned int* __restrict__ bucketptr,
                       const uint2* __restrict__ payload,
                       const unsigned int* __restrict__ xh,
                       float* __restrict__ out, int n) {
    __shared__ float acc[TGRP * D_FEAT];   // 20 KB
    const int b    = blockIdx.x;
    const int tid  = threadIdx.x;
    const int wv   = tid >> 6;
    const int lane = tid & 63;

    for (int i = tid; i < TGRP * D_FEAT; i += 1024) acc[i] = 0.f;
    __syncthreads();

    const int beg = (int)bucketptr[b];
    const int end = (int)bucketptr[b + 1];

    for (int bs = beg + wv * 64; bs < end; bs += 16 * 64) {
        int cnt = end - bs;
        if (cnt > 64) cnt = 64;
        uint2 p = make_uint2(0u, 0u);
        if (lane < cnt) p = payload[bs + lane];

        int j = 0;
        for (; j + 3 < cnt; j += 4) {
            unsigned int px[4], py[4];
            #pragma unroll
            for (int q = 0; q < 4; ++q) {
                px[q] = (unsigned int)__shfl((int)p.x, j + q, 64);
                py[q] = (unsigned int)__shfl((int)p.y, j + q, 64);
            }
            unsigned int xu[4];
            #pragma unroll
            for (int q = 0; q < 4; ++q)
                xu[q] = xh[(size_t)(px[q] >> 16) * 64 + lane];
            #pragma unroll
            for (int q = 0; q < 4; ++q) {
                float w = __half2float(__ushort_as_half((unsigned short)(px[q] & 0xffffu)));
                float2 f = h2_to_f2(xu[q]);
                atomicAdd(&acc[py[q] * D_FEAT + 2 * lane],     f.x * w);
                atomicAdd(&acc[py[q] * D_FEAT + 2 * lane + 1], f.y * w);
            }
        }
        for (; j < cnt; ++j) {
            unsigned int px = (unsigned int)__shfl((int)p.x, j, 64);
            unsigned int py = (unsigned int)__shfl((int)p.y, j, 64);
            float w = __half2float(__ushort_as_half((unsigned short)(px & 0xffffu)));
            unsigned int xu = xh[(size_t)(px >> 16) * 64 + lane];
            float2 f = h2_to_f2(xu);
            atomicAdd(&acc[py * D_FEAT + 2 * lane],     f.x * w);
            atomicAdd(&acc[py * D_FEAT + 2 * lane + 1], f.y * w);
        }
    }
    __syncthreads();

    // relu + L2 normalize + coalesced store (1/deg cancels)
    const int t0 = b * TGRP;
    int tmax = n - t0;
    if (tmax > TGRP) tmax = TGRP;
    for (int r = wv; r < tmax; r += 16) {
        float v0 = acc[r * D_FEAT + 2 * lane];
        float v1 = acc[r * D_FEAT + 2 * lane + 1];
        v0 = fmaxf(v0, 0.f);
        v1 = fmaxf(v1, 0.f);
        float ss = v0 * v0 + v1 * v1;
        #pragma unroll
        for (int off = 32; off > 0; off >>= 1) ss += __shfl_xor(ss, off, 64);
        float sc = 1.0f / fmaxf(sqrtf(ss), EPS);
        float2 o = make_float2(v0 * sc, v1 * sc);
        ((float2*)out)[(size_t)(t0 + r) * 64 + lane] = o;
    }
}

// ===========================================================================
// Last-resort fallback (proven R1): atomic scatter, needs n*4 B of ws.
// ===========================================================================
__global__ void deg_kernel(const int* __restrict__ edge_i,
                           const float* __restrict__ ew,
                           float* __restrict__ deg, int E) {
    int e = blockIdx.x * blockDim.x + threadIdx.x;
    if (e < E) atomicAdd(&deg[edge_i[e]], ew[e]);
}

__global__ void scatter_kernel(const int* __restrict__ edge_j,
                               const int* __restrict__ edge_i,
                               const float* __restrict__ ew,
                               const float* __restrict__ deg,
                               const float* __restrict__ x,
                               float* __restrict__ out, int E) {
    int wave = (int)((blockIdx.x * (unsigned)blockDim.x + threadIdx.x) >> 6);
    int lane = threadIdx.x & 63;
    if (wave >= E) return;
    int tgt = edge_i[wave];
    int src = edge_j[wave];
    float w = ew[wave] / deg[tgt];
    const float2* xr = (const float2*)(x + (size_t)src * D_FEAT);
    float2 v = xr[lane];
    float* o = out + (size_t)tgt * D_FEAT + lane * 2;
    atomicAdd(o,     v.x * w);
    atomicAdd(o + 1, v.y * w);
}

__global__ void norm_kernel(float* __restrict__ out, int n) {
    int row = (int)((blockIdx.x * (unsigned)blockDim.x + threadIdx.x) >> 6);
    int lane = threadIdx.x & 63;
    if (row >= n) return;
    float2* o = (float2*)(out + (size_t)row * D_FEAT);
    float2 v = o[lane];
    v.x = fmaxf(v.x, 0.0f);
    v.y = fmaxf(v.y, 0.0f);
    float ss = v.x * v.x + v.y * v.y;
    #pragma unroll
    for (int off = 32; off > 0; off >>= 1) ss += __shfl_xor(ss, off, 64);
    float scale = 1.0f / fmaxf(sqrtf(ss), EPS);
    v.x *= scale;
    v.y *= scale;
    o[lane] = v;
}

// ===========================================================================
// Launch. ws layout (64 B aligned):
//   xh (2.56 MB) | cntb (128 KB) | baseb (128 KB) | bucketptr (~1 KB)
//   | payload uint2 (E*8 = 5.12 MB)    total ~8 MB (ws is 256 MiB).
// Guards: E % NBLK == 0, E/NBLK <= EPB_MAX, n <= NBUCK_PAD*TGRP.
// ===========================================================================
static inline size_t align64(size_t v) { return (v + 63) & ~(size_t)63; }

extern "C" void kernel_launch(void* const* d_in, const int* in_sizes, int n_in,
                              void* d_out, int out_size, void* d_ws, size_t ws_size,
                              hipStream_t stream) {
    const float* x    = (const float*)d_in[0];
    const int*   edge = (const int*)d_in[1];
    const float* ew   = (const float*)d_in[2];
    float*       out  = (float*)d_out;

    const int E = in_sizes[2];            // 640000
    const int n = in_sizes[0] / D_FEAT;   // 10000

    const int* edge_j = edge;                    // sources (row 0)
    const int* edge_i = edge + 2 * (size_t)E;    // targets (row 2)

    const int EPB   = E / NBLK;                  // 2560
    const int nbuck = (n + TGRP - 1) / TGRP;     // 250

    const size_t off_cntb  = align64((size_t)n * D_FEAT * 2);
    const size_t off_baseb = align64(off_cntb + (size_t)NBLK * NBUCK_PAD * 2);
    const size_t off_bp    = align64(off_baseb + (size_t)NBLK * NBUCK_PAD * 2);
    const size_t off_pl    = align64(off_bp + (size_t)(NBUCK_PAD + 1) * 4);
    const size_t need      = off_pl + (size_t)E * 8;

    if (ws_size >= need && (E % NBLK) == 0 && EPB <= EPB_MAX &&
        n <= NBUCK_PAD * TGRP && nbuck <= NBUCK_PAD) {
        char* ws = (char*)d_ws;
        unsigned int*   xh        = (unsigned int*)ws;
        unsigned short* cntb      = (unsigned short*)(ws + off_cntb);
        unsigned short* baseb     = (unsigned short*)(ws + off_baseb);
        unsigned int*   bucketptr = (unsigned int*)(ws + off_bp);
        uint2*          payload   = (uint2*)(ws + off_pl);

        const int total4 = n * D_FEAT / 4;   // 320000 float4 groups

        count_convert_kernel<<<NBLK, 1024, 0, stream>>>(edge_i, x, xh, cntb,
                                                        E, total4);
        prefix_kernel<<<1, 256, 0, stream>>>(cntb, baseb, bucketptr, nbuck);
        partition_kernel<<<NBLK, 1024, 0, stream>>>(edge_i, edge_j, ew, baseb,
                                                    bucketptr, payload, E);
        accum_norm_kernel<<<nbuck, 1024, 0, stream>>>(bucketptr, payload, xh,
                                                      out, n);
    } else {
        float* deg = (float*)d_ws;
        hipMemsetAsync(deg, 0, (size_t)n * sizeof(float), stream);
        hipMemsetAsync(out, 0, (size_t)out_size * sizeof(float), stream);
        deg_kernel<<<(E + 255) / 256, 256, 0, stream>>>(edge_i, ew, deg, E);
        scatter_kernel<<<(E + 3) / 4, 256, 0, stream>>>(edge_j, edge_i, ew, deg, x, out, E);
        norm_kernel<<<(n + 3) / 4, 256, 0, stream>>>(out, n);
    }
}

// Round 17
// 104.595 us; speedup vs baseline: 5.1892x; 5.1892x over previous
//
#include <hip/hip_runtime.h>
#include <hip/hip_fp16.h>
#include <math.h>

#define D_FEAT 128
#define EPS 1e-12f
#define TGRP 40        // targets per bucket; 250 buckets for n=10000
#define NBUCK_PAD 256  // padded bucket count
#define NBLK 250       // edge chunks; EPB = E/NBLK = 2560
#define EPB_MAX 2560   // LDS staging capacity in partition kernel
#define LCAP 3584      // per-bucket segment cap in sort kernel (Poisson 2560,
                       // +20 sigma; overflow clamped for memory safety)

// ===========================================================================
// out = normalize(relu(sum_e ew_e * x_src)) — 1/deg cancels in the normalize.
// R17: two-pass coalesced counting sort + proven gather.
//   P1 count+convert: per-chunk LDS hist over 250 buckets -> cntb u16;
//      fused x->fp16 convert.                                   [R16 proven]
//   PB prefix: baseb[chunk][bucket] u16, bucketptr u32.         [R16 proven]
//   P2 partition by bucket: LDS-staged, writes uint2{srcw,tloc} in ~10-edge
//      coalesced runs (kills place_kernel's 34 MB scattered-store
//      write-through).                                          [R16 proven]
//   P3 per-bucket counting sort by the 40 local targets: ONE LDS atomic per
//      edge (rank only — R16's 128 per-feature LDS atomics/edge was 461 us),
//      fully coalesced read + write of the final srcw stream; exact rowptr.
//   G  R15-proven 16-lane-group uint4 gather + relu + L2norm, via rowptr.
// Zero global atomics, zero scattered small stores, no memsets.
// ===========================================================================

__device__ inline float2 h2_to_f2(unsigned int u) {
    __half2 h = *reinterpret_cast<__half2*>(&u);
    return __half22float2(h);
}

// ---------------------------------------------------------------------------
// P1: per-chunk bucket histogram + fused x fp32->fp16 convert.
// ---------------------------------------------------------------------------
__global__ __launch_bounds__(1024)
void count_convert_kernel(const int* __restrict__ edge_i,
                          const float* __restrict__ x,
                          unsigned int* __restrict__ xh,
                          unsigned short* __restrict__ cntb,  // [NBLK][NBUCK_PAD]
                          int E, int total4) {
    __shared__ unsigned int hc[NBUCK_PAD];
    const int b   = blockIdx.x;
    const int tid = threadIdx.x;
    const int EPB = E / NBLK;

    if (tid < NBUCK_PAD) hc[tid] = 0;
    __syncthreads();

    for (int i = b * 1024 + tid; i < total4; i += NBLK * 1024) {
        float4 v = ((const float4*)x)[i];
        __half2 h01 = __floats2half2_rn(v.x, v.y);
        __half2 h23 = __floats2half2_rn(v.z, v.w);
        uint2 o;
        o.x = *reinterpret_cast<unsigned int*>(&h01);
        o.y = *reinterpret_cast<unsigned int*>(&h23);
        ((uint2*)xh)[i] = o;
    }

    const int e0 = b * EPB;
    for (int k = tid; k < EPB; k += 1024)
        atomicAdd(&hc[edge_i[e0 + k] / TGRP], 1u);
    __syncthreads();

    if (tid < NBUCK_PAD)
        cntb[(size_t)b * NBUCK_PAD + tid] =
            (unsigned short)(hc[tid] > 65535u ? 65535u : hc[tid]);
}

// ---------------------------------------------------------------------------
// PB: per-bucket prefix over chunks (baseb) + bucket offsets (bucketptr).
// ---------------------------------------------------------------------------
__global__ __launch_bounds__(256)
void prefix_kernel(const unsigned short* __restrict__ cntb,
                   unsigned short* __restrict__ baseb,   // [NBLK][NBUCK_PAD]
                   unsigned int* __restrict__ bucketptr, // [nbuck+1]
                   int nbuck) {
    __shared__ unsigned int s[256];
    const int tid = threadIdx.x;
    unsigned int tot = 0;
    if (tid < nbuck) {
        for (int c = 0; c < NBLK; ++c) {
            unsigned int v = cntb[(size_t)c * NBUCK_PAD + tid];
            baseb[(size_t)c * NBUCK_PAD + tid] = (unsigned short)tot;
            tot += v;
        }
    }
    s[tid] = (tid < nbuck) ? tot : 0;
    __syncthreads();
    for (int off = 1; off < 256; off <<= 1) {
        unsigned int v = (tid >= off) ? s[tid - off] : 0;
        __syncthreads();
        s[tid] += v;
        __syncthreads();
    }
    if (tid < nbuck) bucketptr[tid] = s[tid] - tot;  // exclusive
    if (tid == 255) bucketptr[nbuck] = s[255];       // grand total
}

// ---------------------------------------------------------------------------
// P2: partition by bucket. LDS-staged; writes coalesced per-(chunk,bucket)
// runs of uint2{src<<16|fp16(w), tloc}.
// ---------------------------------------------------------------------------
__global__ __launch_bounds__(1024)
void partition_kernel(const int* __restrict__ edge_i,
                      const int* __restrict__ edge_j,
                      const float* __restrict__ ew,
                      const unsigned short* __restrict__ baseb,
                      const unsigned int* __restrict__ bucketptr,
                      uint2* __restrict__ payload, int E) {
    __shared__ unsigned int hc[NBUCK_PAD];
    __shared__ unsigned int hbase[NBUCK_PAD];
    __shared__ unsigned int stmp[NBUCK_PAD];
    __shared__ uint2        sp[EPB_MAX];     // 20 KB
    __shared__ unsigned int sdst[EPB_MAX];   // 10 KB
    const int b   = blockIdx.x;
    const int tid = threadIdx.x;
    const int EPB = E / NBLK;
    const int e0  = b * EPB;

    if (tid < NBUCK_PAD) hc[tid] = 0;
    __syncthreads();

    int tcar[3]; unsigned int rcar[3]; int kcar[3]; int ncar = 0;
    for (int k = tid; k < EPB; k += 1024) {
        int t = edge_i[e0 + k];
        unsigned int r = atomicAdd(&hc[t / TGRP], 1u);
        tcar[ncar] = t; rcar[ncar] = r; kcar[ncar] = k; ++ncar;
    }
    __syncthreads();

    unsigned int own = (tid < NBUCK_PAD) ? hc[tid] : 0;
    if (tid < NBUCK_PAD) stmp[tid] = own;
    __syncthreads();
    for (int off = 1; off < NBUCK_PAD; off <<= 1) {
        unsigned int v = (tid >= off && tid < NBUCK_PAD) ? stmp[tid - off] : 0;
        __syncthreads();
        if (tid < NBUCK_PAD) stmp[tid] += v;
        __syncthreads();
    }
    if (tid < NBUCK_PAD) hbase[tid] = stmp[tid] - own;
    __syncthreads();

    for (int c = 0; c < ncar; ++c) {
        int t = tcar[c];
        int k = kcar[c];
        unsigned int r = rcar[c];
        int bkt  = t / TGRP;
        int tloc = t - bkt * TGRP;
        int e = e0 + k;
        unsigned short hw = __half_as_ushort(__float2half(ew[e]));
        unsigned int lpos = hbase[bkt] + r;
        sp[lpos]   = make_uint2(((unsigned int)edge_j[e] << 16) | (unsigned int)hw,
                                (unsigned int)tloc);
        sdst[lpos] = bucketptr[bkt] + (unsigned int)baseb[(size_t)b * NBUCK_PAD + bkt] + r;
    }
    __syncthreads();

    for (int k = tid; k < EPB; k += 1024)
        payload[sdst[k]] = sp[k];
}

// ---------------------------------------------------------------------------
// P3: per-bucket counting sort by 40 local targets. One LDS atomic per edge
// (rank); coalesced read of uint2 segment, coalesced write of sorted srcw;
// writes exact rowptr for its 40 targets.
// ---------------------------------------------------------------------------
__global__ __launch_bounds__(1024)
void sort_bucket_kernel(const unsigned int* __restrict__ bucketptr,
                        const uint2* __restrict__ payload,
                        unsigned int* __restrict__ srcw_sorted,
                        int* __restrict__ rowptr,
                        int n, int nbuck) {
    __shared__ unsigned int cnt40[TGRP];
    __shared__ unsigned int base40[TGRP + 1];
    __shared__ unsigned int ssw[LCAP];   // 14 KB
    const int b   = blockIdx.x;
    const int tid = threadIdx.x;

    if (tid < TGRP) cnt40[tid] = 0;
    __syncthreads();

    const int beg = (int)bucketptr[b];
    const int end = (int)bucketptr[b + 1];
    int L = end - beg;
    if (L > LCAP) L = LCAP;   // never expected (Poisson 2560 vs 3584)

    // pass 1: load + rank (<= 4 edges/thread carried in registers)
    unsigned int swc[4]; int tlc[4]; unsigned int rc[4]; int ncar = 0;
    for (int k = tid; k < L; k += 1024) {
        uint2 pl = payload[beg + k];
        unsigned int r = atomicAdd(&cnt40[pl.y], 1u);
        swc[ncar] = pl.x; tlc[ncar] = (int)pl.y; rc[ncar] = r; ++ncar;
    }
    __syncthreads();

    // scan the 40 counters (serial on thread 0 — trivial)
    if (tid == 0) {
        unsigned int run = 0;
        for (int r = 0; r < TGRP; ++r) {
            base40[r] = run;
            run += cnt40[r];
        }
        base40[TGRP] = run;
    }
    __syncthreads();

    // rowptr for this bucket's targets
    const int t0 = b * TGRP;
    if (tid < TGRP && t0 + tid < n)
        rowptr[t0 + tid] = beg + (int)base40[tid];
    if (b == nbuck - 1 && tid == 0)
        rowptr[n] = end;

    // pass 2: scatter into LDS (sorted), then dump coalesced
    for (int c = 0; c < ncar; ++c)
        ssw[base40[tlc[c]] + rc[c]] = swc[c];
    __syncthreads();

    for (int k = tid; k < L; k += 1024)
        srcw_sorted[beg + k] = ssw[k];
}

// ---------------------------------------------------------------------------
// G: gather + relu + L2 normalize (R15-proven 16-lane-group uint4 form),
// indexed by rowptr. wave = 4 groups x 16 lanes; lane l16 owns feats
// [8*l16, 8*l16+8); group g consumes edges {it*4+g}.
// ---------------------------------------------------------------------------
__global__ __launch_bounds__(256)
void gather_norm_kernel(const int* __restrict__ rowptr,
                        const unsigned int* __restrict__ srcw_sorted,
                        const unsigned int* __restrict__ xh,
                        float* __restrict__ out, int n) {
    int row  = (int)((blockIdx.x * (unsigned)blockDim.x + threadIdx.x) >> 6);
    int lane = threadIdx.x & 63;
    if (row >= n) return;

    const int beg = rowptr[row];
    const int m   = rowptr[row + 1] - beg;

    const unsigned int* __restrict__ prow = srcw_sorted + beg;
    const uint4* __restrict__ xr = (const uint4*)xh;  // 8 fp16 per uint4
    const int g   = lane >> 4;
    const int l16 = lane & 15;

    float4 accA = {0.f,0.f,0.f,0.f};
    float4 accB = {0.f,0.f,0.f,0.f};

    for (int base = 0; base < m; base += 64) {
        int mm = m - base;
        if (mm > 64) mm = 64;
        unsigned int p = 0;
        if (lane < mm) p = prow[base + lane];

        const int itmax = (mm + 3) >> 2;
        int it = 0;
        for (; it + 3 < itmax; it += 4) {
            unsigned int pj[4];
            #pragma unroll
            for (int q = 0; q < 4; ++q)
                pj[q] = (unsigned int)__shfl((int)p, (it + q) * 4 + g, 64);
            uint4 h[4];
            #pragma unroll
            for (int q = 0; q < 4; ++q)
                h[q] = xr[(size_t)(pj[q] >> 16) * 16 + l16];
            #pragma unroll
            for (int q = 0; q < 4; ++q) {
                float w = __half2float(__ushort_as_half((unsigned short)(pj[q] & 0xffffu)));
                float2 f;
                f = h2_to_f2(h[q].x); accA.x = fmaf(f.x, w, accA.x); accA.y = fmaf(f.y, w, accA.y);
                f = h2_to_f2(h[q].y); accA.z = fmaf(f.x, w, accA.z); accA.w = fmaf(f.y, w, accA.w);
                f = h2_to_f2(h[q].z); accB.x = fmaf(f.x, w, accB.x); accB.y = fmaf(f.y, w, accB.y);
                f = h2_to_f2(h[q].w); accB.z = fmaf(f.x, w, accB.z); accB.w = fmaf(f.y, w, accB.w);
            }
        }
        for (; it < itmax; ++it) {
            unsigned int pj = (unsigned int)__shfl((int)p, it * 4 + g, 64);
            uint4 h = xr[(size_t)(pj >> 16) * 16 + l16];
            float w = __half2float(__ushort_as_half((unsigned short)(pj & 0xffffu)));
            float2 f;
            f = h2_to_f2(h.x); accA.x = fmaf(f.x, w, accA.x); accA.y = fmaf(f.y, w, accA.y);
            f = h2_to_f2(h.y); accA.z = fmaf(f.x, w, accA.z); accA.w = fmaf(f.y, w, accA.w);
            f = h2_to_f2(h.z); accB.x = fmaf(f.x, w, accB.x); accB.y = fmaf(f.y, w, accB.y);
            f = h2_to_f2(h.w); accB.z = fmaf(f.x, w, accB.z); accB.w = fmaf(f.y, w, accB.w);
        }
    }

    #pragma unroll
    for (int off = 16; off <= 32; off <<= 1) {
        accA.x += __shfl_xor(accA.x, off, 64);
        accA.y += __shfl_xor(accA.y, off, 64);
        accA.z += __shfl_xor(accA.z, off, 64);
        accA.w += __shfl_xor(accA.w, off, 64);
        accB.x += __shfl_xor(accB.x, off, 64);
        accB.y += __shfl_xor(accB.y, off, 64);
        accB.z += __shfl_xor(accB.z, off, 64);
        accB.w += __shfl_xor(accB.w, off, 64);
    }

    accA.x = fmaxf(accA.x, 0.f); accA.y = fmaxf(accA.y, 0.f);
    accA.z = fmaxf(accA.z, 0.f); accA.w = fmaxf(accA.w, 0.f);
    accB.x = fmaxf(accB.x, 0.f); accB.y = fmaxf(accB.y, 0.f);
    accB.z = fmaxf(accB.z, 0.f); accB.w = fmaxf(accB.w, 0.f);

    float ss = accA.x*accA.x + accA.y*accA.y + accA.z*accA.z + accA.w*accA.w
             + accB.x*accB.x + accB.y*accB.y + accB.z*accB.z + accB.w*accB.w;
    #pragma unroll
    for (int off = 8; off > 0; off >>= 1) ss += __shfl_xor(ss, off, 64);

    float scale = 1.0f / fmaxf(sqrtf(ss), EPS);

    if (g == 0) {
        float4 o0 = { accA.x * scale, accA.y * scale, accA.z * scale, accA.w * scale };
        float4 o1 = { accB.x * scale, accB.y * scale, accB.z * scale, accB.w * scale };
        float4* orow = (float4*)out + (size_t)row * 32;
        orow[l16 * 2]     = o0;
        orow[l16 * 2 + 1] = o1;
    }
}

// ===========================================================================
// Last-resort fallback (proven R1): atomic scatter, needs n*4 B of ws.
// ===========================================================================
__global__ void deg_kernel(const int* __restrict__ edge_i,
                           const float* __restrict__ ew,
                           float* __restrict__ deg, int E) {
    int e = blockIdx.x * blockDim.x + threadIdx.x;
    if (e < E) atomicAdd(&deg[edge_i[e]], ew[e]);
}

__global__ void scatter_kernel(const int* __restrict__ edge_j,
                               const int* __restrict__ edge_i,
                               const float* __restrict__ ew,
                               const float* __restrict__ deg,
                               const float* __restrict__ x,
                               float* __restrict__ out, int E) {
    int wave = (int)((blockIdx.x * (unsigned)blockDim.x + threadIdx.x) >> 6);
    int lane = threadIdx.x & 63;
    if (wave >= E) return;
    int tgt = edge_i[wave];
    int src = edge_j[wave];
    float w = ew[wave] / deg[tgt];
    const float2* xr = (const float2*)(x + (size_t)src * D_FEAT);
    float2 v = xr[lane];
    float* o = out + (size_t)tgt * D_FEAT + lane * 2;
    atomicAdd(o,     v.x * w);
    atomicAdd(o + 1, v.y * w);
}

__global__ void norm_kernel(float* __restrict__ out, int n) {
    int row = (int)((blockIdx.x * (unsigned)blockDim.x + threadIdx.x) >> 6);
    int lane = threadIdx.x & 63;
    if (row >= n) return;
    float2* o = (float2*)(out + (size_t)row * D_FEAT);
    float2 v = o[lane];
    v.x = fmaxf(v.x, 0.0f);
    v.y = fmaxf(v.y, 0.0f);
    float ss = v.x * v.x + v.y * v.y;
    #pragma unroll
    for (int off = 32; off > 0; off >>= 1) ss += __shfl_xor(ss, off, 64);
    float scale = 1.0f / fmaxf(sqrtf(ss), EPS);
    v.x *= scale;
    v.y *= scale;
    o[lane] = v;
}

// ===========================================================================
// Launch. ws layout (64 B aligned):
//   xh (2.56 MB) | cntb (128 KB) | baseb (128 KB) | bucketptr (~1 KB)
//   | payload uint2 (5.12 MB) | srcw_sorted (2.56 MB) | rowptr (40 KB)
//   total ~10.5 MB (ws is 256 MiB).
// Guards: E % NBLK == 0, E/NBLK <= EPB_MAX, nbuck <= NBUCK_PAD, n % TGRP ok.
// ===========================================================================
static inline size_t align64(size_t v) { return (v + 63) & ~(size_t)63; }

extern "C" void kernel_launch(void* const* d_in, const int* in_sizes, int n_in,
                              void* d_out, int out_size, void* d_ws, size_t ws_size,
                              hipStream_t stream) {
    const float* x    = (const float*)d_in[0];
    const int*   edge = (const int*)d_in[1];
    const float* ew   = (const float*)d_in[2];
    float*       out  = (float*)d_out;

    const int E = in_sizes[2];            // 640000
    const int n = in_sizes[0] / D_FEAT;   // 10000

    const int* edge_j = edge;                    // sources (row 0)
    const int* edge_i = edge + 2 * (size_t)E;    // targets (row 2)

    const int EPB   = E / NBLK;                  // 2560
    const int nbuck = (n + TGRP - 1) / TGRP;     // 250

    const size_t off_cntb  = align64((size_t)n * D_FEAT * 2);
    const size_t off_baseb = align64(off_cntb + (size_t)NBLK * NBUCK_PAD * 2);
    const size_t off_bp    = align64(off_baseb + (size_t)NBLK * NBUCK_PAD * 2);
    const size_t off_pl    = align64(off_bp + (size_t)(NBUCK_PAD + 1) * 4);
    const size_t off_sw    = align64(off_pl + (size_t)E * 8);
    const size_t off_rp    = align64(off_sw + (size_t)E * 4);
    const size_t need      = off_rp + (size_t)(n + 1) * 4;

    if (ws_size >= need && (E % NBLK) == 0 && EPB <= EPB_MAX &&
        nbuck <= NBUCK_PAD && (size_t)nbuck * TGRP >= (size_t)n) {
        char* ws = (char*)d_ws;
        unsigned int*   xh        = (unsigned int*)ws;
        unsigned short* cntb      = (unsigned short*)(ws + off_cntb);
        unsigned short* baseb     = (unsigned short*)(ws + off_baseb);
        unsigned int*   bucketptr = (unsigned int*)(ws + off_bp);
        uint2*          payload   = (uint2*)(ws + off_pl);
        unsigned int*   srcw      = (unsigned int*)(ws + off_sw);
        int*            rowptr    = (int*)(ws + off_rp);

        const int total4 = n * D_FEAT / 4;   // 320000 float4 groups

        count_convert_kernel<<<NBLK, 1024, 0, stream>>>(edge_i, x, xh, cntb,
                                                        E, total4);
        prefix_kernel<<<1, 256, 0, stream>>>(cntb, baseb, bucketptr, nbuck);
        partition_kernel<<<NBLK, 1024, 0, stream>>>(edge_i, edge_j, ew, baseb,
                                                    bucketptr, payload, E);
        sort_bucket_kernel<<<nbuck, 1024, 0, stream>>>(bucketptr, payload,
                                                       srcw, rowptr, n, nbuck);
        gather_norm_kernel<<<(n + 3) / 4, 256, 0, stream>>>(rowptr, srcw, xh,
                                                            out, n);
    } else {
        float* deg = (float*)d_ws;
        hipMemsetAsync(deg, 0, (size_t)n * sizeof(float), stream);
        hipMemsetAsync(out, 0, (size_t)out_size * sizeof(float), stream);
        deg_kernel<<<(E + 255) / 256, 256, 0, stream>>>(edge_i, ew, deg, E);
        scatter_kernel<<<(E + 3) / 4, 256, 0, stream>>>(edge_j, edge_i, ew, deg, x, out, E);
        norm_kernel<<<(n + 3) / 4, 256, 0, stream>>>(out, n);
    }
}

// Round 18
// 88.853 us; speedup vs baseline: 6.1086x; 1.1772x over previous
//
#include <hip/hip_runtime.h>
#include <hip/hip_fp16.h>
#include <math.h>

#define D_FEAT 128
#define EPS 1e-12f
#define TGRP 40        // targets per bucket; 250 buckets for n=10000
#define NBUCK_PAD 256  // cntcb stride
#define NBLK 250       // edge chunks; EPB = E/NBLK = 2560
#define CAP_CB 40      // payload slots per (chunk,bucket); Poisson(10.24)+9sigma
#define SLOTS_PB (NBLK * CAP_CB)   // 10000 slots per bucket (80 KB)
#define LCAP 3584      // sorted-bucket LDS capacity; Poisson(2560)+20sigma

// ===========================================================================
// out = normalize(relu(sum_e ew_e * x_src)) — 1/deg cancels in the normalize.
// R18: TWO dispatches. R16's decomposition showed the sort FRONT-END + launch
// gaps cost ~81 us (prefix_kernel is single-CU latency; 5-6 launches x ~4 us)
// while the gather is only ~20-25 us. Fix: make all offsets STATIC so no
// cross-block scan exists:
//   payload slot for (chunk c, bucket b, rank r) = b*SLOTS_PB + c*CAP_CB + r
// K1: fused x->fp16 convert + per-chunk LDS hist over 250 buckets (LDS-atomic
//     return = rank) + direct payload write + cntcb[b][c] count table.
// K2 (one block per bucket): masked coalesced read of the padded segment,
//     LDS counting sort by the 40 local targets (ONE LDS atomic per edge —
//     R16's 128/edge was 461 us), then R15-proven 16-lane-group uint4 gather
//     reading srcw from LDS; fused relu + L2 norm + coalesced store.
// Zero global atomics, zero memsets, zero global scans.
// ===========================================================================

__device__ inline float2 h2_to_f2(unsigned int u) {
    __half2 h = *reinterpret_cast<__half2*>(&u);
    return __half22float2(h);
}

// ---------------------------------------------------------------------------
// K1: convert + histogram + direct static-slot payload write.
// ---------------------------------------------------------------------------
__global__ __launch_bounds__(1024)
void build_kernel(const int* __restrict__ edge_i,
                  const int* __restrict__ edge_j,
                  const float* __restrict__ ew,
                  const float* __restrict__ x,
                  unsigned int* __restrict__ xh,
                  unsigned char* __restrict__ cntcb,  // [nbuck][NBUCK_PAD] trans
                  uint2* __restrict__ payload,        // [nbuck][SLOTS_PB]
                  int E, int total4, int nbuck) {
    __shared__ unsigned int hc[NBUCK_PAD];
    const int c   = blockIdx.x;
    const int tid = threadIdx.x;
    const int EPB = E / NBLK;

    if (tid < NBUCK_PAD) hc[tid] = 0;
    __syncthreads();

    // fused fp32 -> fp16 convert (grid-stride)
    for (int i = c * 1024 + tid; i < total4; i += NBLK * 1024) {
        float4 v = ((const float4*)x)[i];
        __half2 h01 = __floats2half2_rn(v.x, v.y);
        __half2 h23 = __floats2half2_rn(v.z, v.w);
        uint2 o;
        o.x = *reinterpret_cast<unsigned int*>(&h01);
        o.y = *reinterpret_cast<unsigned int*>(&h23);
        ((uint2*)xh)[i] = o;
    }

    // per-chunk bucket histogram; rank = slot within (chunk,bucket)
    const int e0 = c * EPB;
    for (int k = tid; k < EPB; k += 1024) {
        int e = e0 + k;
        int t = edge_i[e];
        int bkt  = t / TGRP;
        int tloc = t - bkt * TGRP;
        unsigned int r = atomicAdd(&hc[bkt], 1u);
        if (r < CAP_CB) {
            unsigned short hw = __half_as_ushort(__float2half(ew[e]));
            payload[(size_t)bkt * SLOTS_PB + c * CAP_CB + r] =
                make_uint2(((unsigned int)edge_j[e] << 16) | (unsigned int)hw,
                           (unsigned int)tloc);
        }
    }
    __syncthreads();

    if (tid < nbuck) {
        unsigned int v = hc[tid];
        cntcb[(size_t)tid * NBUCK_PAD + c] =
            (unsigned char)(v > CAP_CB ? CAP_CB : v);
    }
}

// ---------------------------------------------------------------------------
// K2: per-bucket sort (LDS) + gather + relu + L2 norm + store.
// ---------------------------------------------------------------------------
__global__ __launch_bounds__(1024)
void sort_gather_kernel(const unsigned char* __restrict__ cntcb,
                        const uint2* __restrict__ payload,
                        const unsigned int* __restrict__ xh,
                        float* __restrict__ out, int n) {
    __shared__ unsigned char  cnt_c[NBLK];        // per-chunk valid counts
    __shared__ unsigned int   cnt40[TGRP];
    __shared__ unsigned int   base40[TGRP + 1];
    __shared__ unsigned short rank16[SLOTS_PB];   // 20 KB
    __shared__ unsigned int   ssw[LCAP];          // 14 KB
    const int b   = blockIdx.x;
    const int tid = threadIdx.x;
    const int wv   = tid >> 6;
    const int lane = tid & 63;
    const int g    = lane >> 4;    // 16-lane group 0..3
    const int l16  = lane & 15;

    if (tid < NBLK) cnt_c[tid] = cntcb[(size_t)b * NBUCK_PAD + tid];
    if (tid < TGRP) cnt40[tid] = 0;
    __syncthreads();

    const uint2* __restrict__ pb = payload + (size_t)b * SLOTS_PB;

    // pass 1: rank every valid slot by its local target
    for (int s = tid; s < SLOTS_PB; s += 1024) {
        uint2 pl = pb[s];
        int c = s / CAP_CB;
        int k = s - c * CAP_CB;
        if (k < (int)cnt_c[c]) {
            unsigned int r = atomicAdd(&cnt40[pl.y], 1u);
            rank16[s] = (unsigned short)r;
        }
    }
    __syncthreads();

    if (tid == 0) {
        unsigned int run = 0;
        for (int t = 0; t < TGRP; ++t) { base40[t] = run; run += cnt40[t]; }
        base40[TGRP] = run;
    }
    __syncthreads();

    // pass 2: scatter srcw into sorted LDS order (payload reread is L2-hot)
    for (int s = tid; s < SLOTS_PB; s += 1024) {
        uint2 pl = pb[s];
        int c = s / CAP_CB;
        int k = s - c * CAP_CB;
        if (k < (int)cnt_c[c]) {
            unsigned int pos = base40[pl.y] + (unsigned int)rank16[s];
            if (pos < LCAP) ssw[pos] = pl.x;
        }
    }
    __syncthreads();

    // gather: wave wv handles local targets wv, wv+16, ... (R15-proven form)
    const uint4* __restrict__ xr = (const uint4*)xh;  // 8 fp16 per uint4
    for (int tl = wv; tl < TGRP; tl += 16) {
        int t = b * TGRP + tl;
        if (t >= n) break;
        int beg = (int)base40[tl];
        int m   = (int)cnt40[tl];
        if (beg + m > LCAP) m = (LCAP - beg > 0) ? (LCAP - beg) : 0;  // safety

        float4 accA = {0.f,0.f,0.f,0.f};
        float4 accB = {0.f,0.f,0.f,0.f};

        int it = 0;
        for (; it + 15 < m; it += 16) {
            unsigned int pq[4]; uint4 hq[4];
            #pragma unroll
            for (int q = 0; q < 4; ++q) pq[q] = ssw[beg + it + q * 4 + g];
            #pragma unroll
            for (int q = 0; q < 4; ++q) hq[q] = xr[(size_t)(pq[q] >> 16) * 16 + l16];
            #pragma unroll
            for (int q = 0; q < 4; ++q) {
                float w = __half2float(__ushort_as_half((unsigned short)(pq[q] & 0xffffu)));
                float2 f;
                f = h2_to_f2(hq[q].x); accA.x = fmaf(f.x, w, accA.x); accA.y = fmaf(f.y, w, accA.y);
                f = h2_to_f2(hq[q].y); accA.z = fmaf(f.x, w, accA.z); accA.w = fmaf(f.y, w, accA.w);
                f = h2_to_f2(hq[q].z); accB.x = fmaf(f.x, w, accB.x); accB.y = fmaf(f.y, w, accB.y);
                f = h2_to_f2(hq[q].w); accB.z = fmaf(f.x, w, accB.z); accB.w = fmaf(f.y, w, accB.w);
            }
        }
        for (; it < m; it += 4) {
            int idx = it + g;
            unsigned int p = (idx < m) ? ssw[beg + idx] : 0u;  // w=0 pad
            uint4 h = xr[(size_t)(p >> 16) * 16 + l16];
            float w = __half2float(__ushort_as_half((unsigned short)(p & 0xffffu)));
            float2 f;
            f = h2_to_f2(h.x); accA.x = fmaf(f.x, w, accA.x); accA.y = fmaf(f.y, w, accA.y);
            f = h2_to_f2(h.y); accA.z = fmaf(f.x, w, accA.z); accA.w = fmaf(f.y, w, accA.w);
            f = h2_to_f2(h.z); accB.x = fmaf(f.x, w, accB.x); accB.y = fmaf(f.y, w, accB.y);
            f = h2_to_f2(h.w); accB.z = fmaf(f.x, w, accB.z); accB.w = fmaf(f.y, w, accB.w);
        }

        // combine the 4 groups
        #pragma unroll
        for (int off = 16; off <= 32; off <<= 1) {
            accA.x += __shfl_xor(accA.x, off, 64);
            accA.y += __shfl_xor(accA.y, off, 64);
            accA.z += __shfl_xor(accA.z, off, 64);
            accA.w += __shfl_xor(accA.w, off, 64);
            accB.x += __shfl_xor(accB.x, off, 64);
            accB.y += __shfl_xor(accB.y, off, 64);
            accB.z += __shfl_xor(accB.z, off, 64);
            accB.w += __shfl_xor(accB.w, off, 64);
        }

        accA.x = fmaxf(accA.x, 0.f); accA.y = fmaxf(accA.y, 0.f);
        accA.z = fmaxf(accA.z, 0.f); accA.w = fmaxf(accA.w, 0.f);
        accB.x = fmaxf(accB.x, 0.f); accB.y = fmaxf(accB.y, 0.f);
        accB.z = fmaxf(accB.z, 0.f); accB.w = fmaxf(accB.w, 0.f);

        float ss = accA.x*accA.x + accA.y*accA.y + accA.z*accA.z + accA.w*accA.w
                 + accB.x*accB.x + accB.y*accB.y + accB.z*accB.z + accB.w*accB.w;
        #pragma unroll
        for (int off = 8; off > 0; off >>= 1) ss += __shfl_xor(ss, off, 64);

        float scale = 1.0f / fmaxf(sqrtf(ss), EPS);

        if (g == 0) {
            float4 o0 = { accA.x * scale, accA.y * scale, accA.z * scale, accA.w * scale };
            float4 o1 = { accB.x * scale, accB.y * scale, accB.z * scale, accB.w * scale };
            float4* orow = (float4*)out + (size_t)t * 32;
            orow[l16 * 2]     = o0;
            orow[l16 * 2 + 1] = o1;
        }
    }
}

// ===========================================================================
// Last-resort fallback (proven R1): atomic scatter, needs n*4 B of ws.
// ===========================================================================
__global__ void deg_kernel(const int* __restrict__ edge_i,
                           const float* __restrict__ ew,
                           float* __restrict__ deg, int E) {
    int e = blockIdx.x * blockDim.x + threadIdx.x;
    if (e < E) atomicAdd(&deg[edge_i[e]], ew[e]);
}

__global__ void scatter_kernel(const int* __restrict__ edge_j,
                               const int* __restrict__ edge_i,
                               const float* __restrict__ ew,
                               const float* __restrict__ deg,
                               const float* __restrict__ x,
                               float* __restrict__ out, int E) {
    int wave = (int)((blockIdx.x * (unsigned)blockDim.x + threadIdx.x) >> 6);
    int lane = threadIdx.x & 63;
    if (wave >= E) return;
    int tgt = edge_i[wave];
    int src = edge_j[wave];
    float w = ew[wave] / deg[tgt];
    const float2* xr = (const float2*)(x + (size_t)src * D_FEAT);
    float2 v = xr[lane];
    float* o = out + (size_t)tgt * D_FEAT + lane * 2;
    atomicAdd(o,     v.x * w);
    atomicAdd(o + 1, v.y * w);
}

__global__ void norm_kernel(float* __restrict__ out, int n) {
    int row = (int)((blockIdx.x * (unsigned)blockDim.x + threadIdx.x) >> 6);
    int lane = threadIdx.x & 63;
    if (row >= n) return;
    float2* o = (float2*)(out + (size_t)row * D_FEAT);
    float2 v = o[lane];
    v.x = fmaxf(v.x, 0.0f);
    v.y = fmaxf(v.y, 0.0f);
    float ss = v.x * v.x + v.y * v.y;
    #pragma unroll
    for (int off = 32; off > 0; off >>= 1) ss += __shfl_xor(ss, off, 64);
    float scale = 1.0f / fmaxf(sqrtf(ss), EPS);
    v.x *= scale;
    v.y *= scale;
    o[lane] = v;
}

// ===========================================================================
// Launch. ws layout (64 B aligned):
//   xh (n*256 B = 2.56 MB) | cntcb (nbuck*256 = 64 KB)
//   | payload (nbuck*SLOTS_PB*8 = 20 MB)     total ~22.6 MB (ws is 256 MiB).
// Guards: E % NBLK == 0, nbuck <= NBLK, n <= nbuck*TGRP.
// ===========================================================================
static inline size_t align64(size_t v) { return (v + 63) & ~(size_t)63; }

extern "C" void kernel_launch(void* const* d_in, const int* in_sizes, int n_in,
                              void* d_out, int out_size, void* d_ws, size_t ws_size,
                              hipStream_t stream) {
    const float* x    = (const float*)d_in[0];
    const int*   edge = (const int*)d_in[1];
    const float* ew   = (const float*)d_in[2];
    float*       out  = (float*)d_out;

    const int E = in_sizes[2];            // 640000
    const int n = in_sizes[0] / D_FEAT;   // 10000

    const int* edge_j = edge;                    // sources (row 0)
    const int* edge_i = edge + 2 * (size_t)E;    // targets (row 2)

    const int nbuck = (n + TGRP - 1) / TGRP;     // 250

    const size_t off_cnt = align64((size_t)n * D_FEAT * 2);
    const size_t off_pl  = align64(off_cnt + (size_t)nbuck * NBUCK_PAD);
    const size_t need    = off_pl + (size_t)nbuck * SLOTS_PB * 8;

    if (ws_size >= need && (E % NBLK) == 0 && nbuck <= NBLK &&
        (size_t)nbuck * TGRP >= (size_t)n && nbuck <= NBUCK_PAD) {
        char* ws = (char*)d_ws;
        unsigned int*  xh      = (unsigned int*)ws;
        unsigned char* cntcb   = (unsigned char*)(ws + off_cnt);
        uint2*         payload = (uint2*)(ws + off_pl);

        const int total4 = n * D_FEAT / 4;   // 320000 float4 groups

        build_kernel<<<NBLK, 1024, 0, stream>>>(edge_i, edge_j, ew, x, xh,
                                                cntcb, payload, E, total4, nbuck);
        sort_gather_kernel<<<nbuck, 1024, 0, stream>>>(cntcb, payload, xh,
                                                       out, n);
    } else {
        float* deg = (float*)d_ws;
        hipMemsetAsync(deg, 0, (size_t)n * sizeof(float), stream);
        hipMemsetAsync(out, 0, (size_t)out_size * sizeof(float), stream);
        deg_kernel<<<(E + 255) / 256, 256, 0, stream>>>(edge_i, ew, deg, E);
        scatter_kernel<<<(E + 3) / 4, 256, 0, stream>>>(edge_j, edge_i, ew, deg, x, out, E);
        norm_kernel<<<(n + 3) / 4, 256, 0, stream>>>(out, n);
    }
}

// Round 19
// 87.015 us; speedup vs baseline: 6.2376x; 1.0211x over previous
//
#include <hip/hip_runtime.h>
#include <hip/hip_fp16.h>
#include <math.h>

#define D_FEAT 128
#define EPS 1e-12f
#define TGRP 40        // targets per bucket; 250 buckets for n=10000
#define NBUCK_PAD 256  // cntcb stride
#define NBLK 250       // edge chunks; EPB = E/NBLK = 2560
#define CAP_CB 40      // payload slots per (chunk,bucket); Poisson(10.24)+~9sigma
#define SLOTS_PB (NBLK * CAP_CB)   // 10000 slots per bucket (40 KB at u32)
#define LCAP 3584      // per-bucket LDS capacity; Poisson(2560)+20sigma

// ===========================================================================
// out = normalize(relu(sum_e ew_e * x_src)) — 1/deg cancels in the normalize.
// R19 = R18 (2-dispatch static-offset sort, proven 88.9us) with the payload
// round-trip cut in half twice:
//   * payload packed to 4 B: src(14)<<18 | tloc(6)<<12 | w12(12), where w12 =
//     rounded top 12 bits of fp16(w) (<=2^-8 rel err; absmax impact ~1e-4).
//     Padded payload 20 MB -> 10 MB; K1 scattered-write bytes halve.
//   * K2 reads the padded segment ONCE: pass 1 compacts valid slots into LDS
//     while ranking (2 LDS atomics/edge); pass 2 sorted-scatter is LDS->LDS.
// K1: fused x->fp16 convert + per-chunk LDS hist (rank = static slot) +
//     direct payload write + cntcb count table.
// K2: per-bucket compact+rank -> 40-counter scan -> LDS sorted scatter ->
//     R15-proven 16-lane-group uint4 gather + relu + L2norm + store.
// Zero global atomics, zero memsets, zero global scans, 2 dispatches.
// ===========================================================================

__device__ inline float2 h2_to_f2(unsigned int u) {
    __half2 h = *reinterpret_cast<__half2*>(&u);
    return __half22float2(h);
}

__device__ inline float w12_to_f(unsigned int p) {
    return __half2float(__ushort_as_half((unsigned short)((p & 0xfffu) << 4)));
}

// ---------------------------------------------------------------------------
// K1: convert + histogram + direct static-slot payload write (4 B packed).
// ---------------------------------------------------------------------------
__global__ __launch_bounds__(1024)
void build_kernel(const int* __restrict__ edge_i,
                  const int* __restrict__ edge_j,
                  const float* __restrict__ ew,
                  const float* __restrict__ x,
                  unsigned int* __restrict__ xh,
                  unsigned char* __restrict__ cntcb,   // [nbuck][NBUCK_PAD]
                  unsigned int* __restrict__ payload,  // [nbuck][SLOTS_PB]
                  int E, int total4, int nbuck) {
    __shared__ unsigned int hc[NBUCK_PAD];
    const int c   = blockIdx.x;
    const int tid = threadIdx.x;
    const int EPB = E / NBLK;

    if (tid < NBUCK_PAD) hc[tid] = 0;
    __syncthreads();

    // fused fp32 -> fp16 convert (grid-stride)
    for (int i = c * 1024 + tid; i < total4; i += NBLK * 1024) {
        float4 v = ((const float4*)x)[i];
        __half2 h01 = __floats2half2_rn(v.x, v.y);
        __half2 h23 = __floats2half2_rn(v.z, v.w);
        uint2 o;
        o.x = *reinterpret_cast<unsigned int*>(&h01);
        o.y = *reinterpret_cast<unsigned int*>(&h23);
        ((uint2*)xh)[i] = o;
    }

    // per-chunk bucket histogram; rank = static slot within (chunk,bucket)
    const int e0 = c * EPB;
    for (int k = tid; k < EPB; k += 1024) {
        int e = e0 + k;
        int t = edge_i[e];
        int bkt  = t / TGRP;
        int tloc = t - bkt * TGRP;
        unsigned int r = atomicAdd(&hc[bkt], 1u);
        if (r < CAP_CB) {
            unsigned int hw = (unsigned int)__half_as_ushort(__float2half(ew[e]));
            unsigned int w12 = (hw + 8u) >> 4;   // round-to-nearest 12-bit fp16
            payload[(size_t)bkt * SLOTS_PB + c * CAP_CB + r] =
                ((unsigned int)edge_j[e] << 18) | ((unsigned int)tloc << 12) | w12;
        }
    }
    __syncthreads();

    if (tid < nbuck) {
        unsigned int v = hc[tid];
        cntcb[(size_t)tid * NBUCK_PAD + c] =
            (unsigned char)(v > CAP_CB ? CAP_CB : v);
    }
}

// ---------------------------------------------------------------------------
// K2: per-bucket compact+rank (single global read) -> LDS sort -> gather +
// relu + L2 norm + store.
// ---------------------------------------------------------------------------
__global__ __launch_bounds__(1024)
void sort_gather_kernel(const unsigned char* __restrict__ cntcb,
                        const unsigned int* __restrict__ payload,
                        const unsigned int* __restrict__ xh,
                        float* __restrict__ out, int n) {
    __shared__ unsigned char cnt_c[NBLK];
    __shared__ unsigned int  cnt40[TGRP];
    __shared__ unsigned int  base40[TGRP + 1];
    __shared__ unsigned int  ccnt;
    __shared__ unsigned int  lpl[LCAP];   // compacted packed payload  (14 KB)
    __shared__ unsigned int  lpd[LCAP];   // tloc<<16 | rank           (14 KB)
    __shared__ unsigned int  ssw[LCAP];   // target-sorted payload     (14 KB)
    const int b    = blockIdx.x;
    const int tid  = threadIdx.x;
    const int wv   = tid >> 6;
    const int lane = tid & 63;
    const int g    = lane >> 4;    // 16-lane group 0..3
    const int l16  = lane & 15;

    if (tid < NBLK) cnt_c[tid] = cntcb[(size_t)b * NBUCK_PAD + tid];
    if (tid < TGRP) cnt40[tid] = 0;
    if (tid == 0) ccnt = 0;
    __syncthreads();

    const unsigned int* __restrict__ pb = payload + (size_t)b * SLOTS_PB;

    // pass 1: single coalesced read of the padded segment; compact + rank
    for (int s = tid; s < SLOTS_PB; s += 1024) {
        unsigned int p = pb[s];
        int c = s / CAP_CB;
        int k = s - c * CAP_CB;
        if (k < (int)cnt_c[c]) {
            unsigned int tloc = (p >> 12) & 63u;
            unsigned int r  = atomicAdd(&cnt40[tloc], 1u);
            unsigned int ci = atomicAdd(&ccnt, 1u);
            if (ci < LCAP) {
                lpl[ci] = p;
                lpd[ci] = (tloc << 16) | (r & 0xffffu);
            }
        }
    }
    __syncthreads();

    if (tid == 0) {
        unsigned int run = 0;
        for (int t = 0; t < TGRP; ++t) { base40[t] = run; run += cnt40[t]; }
        base40[TGRP] = run;
    }
    __syncthreads();

    // pass 2: LDS -> LDS sorted scatter
    unsigned int cc = ccnt;
    if (cc > LCAP) cc = LCAP;
    for (unsigned int i = tid; i < cc; i += 1024) {
        unsigned int d = lpd[i];
        unsigned int pos = base40[d >> 16] + (d & 0xffffu);
        if (pos < LCAP) ssw[pos] = lpl[i];
    }
    __syncthreads();

    // gather: wave wv handles local targets wv, wv+16, ...
    const uint4* __restrict__ xr = (const uint4*)xh;  // 8 fp16 per uint4
    for (int tl = wv; tl < TGRP; tl += 16) {
        int t = b * TGRP + tl;
        if (t >= n) break;
        int beg = (int)base40[tl];
        int m   = (int)cnt40[tl];
        if (beg + m > LCAP) m = (LCAP - beg > 0) ? (LCAP - beg) : 0;  // safety

        float4 accA = {0.f,0.f,0.f,0.f};
        float4 accB = {0.f,0.f,0.f,0.f};

        int it = 0;
        for (; it + 15 < m; it += 16) {
            unsigned int pq[4]; uint4 hq[4];
            #pragma unroll
            for (int q = 0; q < 4; ++q) pq[q] = ssw[beg + it + q * 4 + g];
            #pragma unroll
            for (int q = 0; q < 4; ++q) hq[q] = xr[(size_t)(pq[q] >> 18) * 16 + l16];
            #pragma unroll
            for (int q = 0; q < 4; ++q) {
                float w = w12_to_f(pq[q]);
                float2 f;
                f = h2_to_f2(hq[q].x); accA.x = fmaf(f.x, w, accA.x); accA.y = fmaf(f.y, w, accA.y);
                f = h2_to_f2(hq[q].y); accA.z = fmaf(f.x, w, accA.z); accA.w = fmaf(f.y, w, accA.w);
                f = h2_to_f2(hq[q].z); accB.x = fmaf(f.x, w, accB.x); accB.y = fmaf(f.y, w, accB.y);
                f = h2_to_f2(hq[q].w); accB.z = fmaf(f.x, w, accB.z); accB.w = fmaf(f.y, w, accB.w);
            }
        }
        for (; it < m; it += 4) {
            int idx = it + g;
            unsigned int p = (idx < m) ? ssw[beg + idx] : 0u;  // w=0 pad
            uint4 h = xr[(size_t)(p >> 18) * 16 + l16];
            float w = w12_to_f(p);
            float2 f;
            f = h2_to_f2(h.x); accA.x = fmaf(f.x, w, accA.x); accA.y = fmaf(f.y, w, accA.y);
            f = h2_to_f2(h.y); accA.z = fmaf(f.x, w, accA.z); accA.w = fmaf(f.y, w, accA.w);
            f = h2_to_f2(h.z); accB.x = fmaf(f.x, w, accB.x); accB.y = fmaf(f.y, w, accB.y);
            f = h2_to_f2(h.w); accB.z = fmaf(f.x, w, accB.z); accB.w = fmaf(f.y, w, accB.w);
        }

        #pragma unroll
        for (int off = 16; off <= 32; off <<= 1) {
            accA.x += __shfl_xor(accA.x, off, 64);
            accA.y += __shfl_xor(accA.y, off, 64);
            accA.z += __shfl_xor(accA.z, off, 64);
            accA.w += __shfl_xor(accA.w, off, 64);
            accB.x += __shfl_xor(accB.x, off, 64);
            accB.y += __shfl_xor(accB.y, off, 64);
            accB.z += __shfl_xor(accB.z, off, 64);
            accB.w += __shfl_xor(accB.w, off, 64);
        }

        accA.x = fmaxf(accA.x, 0.f); accA.y = fmaxf(accA.y, 0.f);
        accA.z = fmaxf(accA.z, 0.f); accA.w = fmaxf(accA.w, 0.f);
        accB.x = fmaxf(accB.x, 0.f); accB.y = fmaxf(accB.y, 0.f);
        accB.z = fmaxf(accB.z, 0.f); accB.w = fmaxf(accB.w, 0.f);

        float ss = accA.x*accA.x + accA.y*accA.y + accA.z*accA.z + accA.w*accA.w
                 + accB.x*accB.x + accB.y*accB.y + accB.z*accB.z + accB.w*accB.w;
        #pragma unroll
        for (int off = 8; off > 0; off >>= 1) ss += __shfl_xor(ss, off, 64);

        float scale = 1.0f / fmaxf(sqrtf(ss), EPS);

        if (g == 0) {
            float4 o0 = { accA.x * scale, accA.y * scale, accA.z * scale, accA.w * scale };
            float4 o1 = { accB.x * scale, accB.y * scale, accB.z * scale, accB.w * scale };
            float4* orow = (float4*)out + (size_t)t * 32;
            orow[l16 * 2]     = o0;
            orow[l16 * 2 + 1] = o1;
        }
    }
}

// ===========================================================================
// Last-resort fallback (proven R1): atomic scatter, needs n*4 B of ws.
// ===========================================================================
__global__ void deg_kernel(const int* __restrict__ edge_i,
                           const float* __restrict__ ew,
                           float* __restrict__ deg, int E) {
    int e = blockIdx.x * blockDim.x + threadIdx.x;
    if (e < E) atomicAdd(&deg[edge_i[e]], ew[e]);
}

__global__ void scatter_kernel(const int* __restrict__ edge_j,
                               const int* __restrict__ edge_i,
                               const float* __restrict__ ew,
                               const float* __restrict__ deg,
                               const float* __restrict__ x,
                               float* __restrict__ out, int E) {
    int wave = (int)((blockIdx.x * (unsigned)blockDim.x + threadIdx.x) >> 6);
    int lane = threadIdx.x & 63;
    if (wave >= E) return;
    int tgt = edge_i[wave];
    int src = edge_j[wave];
    float w = ew[wave] / deg[tgt];
    const float2* xr = (const float2*)(x + (size_t)src * D_FEAT);
    float2 v = xr[lane];
    float* o = out + (size_t)tgt * D_FEAT + lane * 2;
    atomicAdd(o,     v.x * w);
    atomicAdd(o + 1, v.y * w);
}

__global__ void norm_kernel(float* __restrict__ out, int n) {
    int row = (int)((blockIdx.x * (unsigned)blockDim.x + threadIdx.x) >> 6);
    int lane = threadIdx.x & 63;
    if (row >= n) return;
    float2* o = (float2*)(out + (size_t)row * D_FEAT);
    float2 v = o[lane];
    v.x = fmaxf(v.x, 0.0f);
    v.y = fmaxf(v.y, 0.0f);
    float ss = v.x * v.x + v.y * v.y;
    #pragma unroll
    for (int off = 32; off > 0; off >>= 1) ss += __shfl_xor(ss, off, 64);
    float scale = 1.0f / fmaxf(sqrtf(ss), EPS);
    v.x *= scale;
    v.y *= scale;
    o[lane] = v;
}

// ===========================================================================
// Launch. ws layout (64 B aligned):
//   xh (2.56 MB) | cntcb (64 KB) | payload u32 (nbuck*SLOTS_PB*4 = 10 MB)
//   total ~12.6 MB (ws is 256 MiB).
// Guards: E % NBLK == 0, nbuck bounds, src < 2^14 (n <= 16384).
// ===========================================================================
static inline size_t align64(size_t v) { return (v + 63) & ~(size_t)63; }

extern "C" void kernel_launch(void* const* d_in, const int* in_sizes, int n_in,
                              void* d_out, int out_size, void* d_ws, size_t ws_size,
                              hipStream_t stream) {
    const float* x    = (const float*)d_in[0];
    const int*   edge = (const int*)d_in[1];
    const float* ew   = (const float*)d_in[2];
    float*       out  = (float*)d_out;

    const int E = in_sizes[2];            // 640000
    const int n = in_sizes[0] / D_FEAT;   // 10000

    const int* edge_j = edge;                    // sources (row 0)
    const int* edge_i = edge + 2 * (size_t)E;    // targets (row 2)

    const int nbuck = (n + TGRP - 1) / TGRP;     // 250

    const size_t off_cnt = align64((size_t)n * D_FEAT * 2);
    const size_t off_pl  = align64(off_cnt + (size_t)nbuck * NBUCK_PAD);
    const size_t need    = off_pl + (size_t)nbuck * SLOTS_PB * 4;

    if (ws_size >= need && (E % NBLK) == 0 && nbuck <= NBLK &&
        (size_t)nbuck * TGRP >= (size_t)n && nbuck <= NBUCK_PAD && n <= 16384) {
        char* ws = (char*)d_ws;
        unsigned int*  xh      = (unsigned int*)ws;
        unsigned char* cntcb   = (unsigned char*)(ws + off_cnt);
        unsigned int*  payload = (unsigned int*)(ws + off_pl);

        const int total4 = n * D_FEAT / 4;   // 320000 float4 groups

        build_kernel<<<NBLK, 1024, 0, stream>>>(edge_i, edge_j, ew, x, xh,
                                                cntcb, payload, E, total4, nbuck);
        sort_gather_kernel<<<nbuck, 1024, 0, stream>>>(cntcb, payload, xh,
                                                       out, n);
    } else {
        float* deg = (float*)d_ws;
        hipMemsetAsync(deg, 0, (size_t)n * sizeof(float), stream);
        hipMemsetAsync(out, 0, (size_t)out_size * sizeof(float), stream);
        deg_kernel<<<(E + 255) / 256, 256, 0, stream>>>(edge_i, ew, deg, E);
        scatter_kernel<<<(E + 3) / 4, 256, 0, stream>>>(edge_j, edge_i, ew, deg, x, out, E);
        norm_kernel<<<(n + 3) / 4, 256, 0, stream>>>(out, n);
    }
}